// Round 5
// baseline (2215.717 us; speedup 1.0000x reference)
//
#include <hip/hip_runtime.h>

// B=128, N=128, L=128 -> BN=16384 rows, T=127 steps, HID=CD=128, HEADS=4.
// v5: (a) hardware transcendentals (v_exp/v_sqrt/v_rcp + acos poly) replacing
// OCML libcalls -- post-mortem of v4 showed ~3x VALU instruction expansion there;
// (b) 1024 blocks x 256 thr, 16 rows/block, 4 blocks/CU (16 waves/CU, balanced);
// (c) weff folded into gat_kernel (1-block weff was ~25us latency-bound).

#define BN_TOT 16384
#define TSTEPS 127
#define LOG2E  1.44269504f

#ifndef __has_builtin
#define __has_builtin(x) 0
#endif
#if __has_builtin(__builtin_amdgcn_exp2f)
#define EXP2F(x) __builtin_amdgcn_exp2f(x)
#else
#define EXP2F(x) exp2f(x)
#endif
#if __has_builtin(__builtin_amdgcn_sqrtf)
#define FSQRT(x) __builtin_amdgcn_sqrtf(x)
#else
#define FSQRT(x) sqrtf(x)
#endif

typedef _Float16 f16x8 __attribute__((ext_vector_type(8)));
typedef float    f32x4 __attribute__((ext_vector_type(4)));

// acos for x in [0,1] (our cos is a product of nonneg terms, clamped above by 1):
// Abramowitz-Stegun 4.4.45, max err ~6.7e-5 rad. 1 v_sqrt + 4 VALU.
__device__ __forceinline__ float acos01(float x) {
    float s = FSQRT(1.0f - x);
    float p = fmaf(x, -0.0187293f, 0.0742610f);
    p = fmaf(x, p, -0.2121144f);
    p = fmaf(x, p, 1.5707288f);
    return s * p;
}

// ---------------------------------------------------------------------------
// Kernel 1: fused features + GRU.
// 1024 blocks x 256 thr (4 waves). Block owns 16 rows; wave wv owns cols
// [32wv, 32wv+32) (c-tiles ct=0,1 -> whh rows wv*32+ct*16+c0, +128, +256).
// whh B-frags register-resident, prescaled by log2e (r,z) / 2*log2e (n) so each
// gate nonlinearity is v_exp + v_rcp. h double-buffered in LDS fp16, XOR swizzle
// (col ^ ((row&7)<<3)), ONE barrier per step. 4 blocks/CU overlap barriers.
// MFMA 16x16x32 f16: A lane l -> row=l&15, k=(l>>4)*8+j ; B lane l -> col=l&15,
// same k ; C lane l reg i -> row=(l>>4)*4+i, col=l&15.
// ---------------------------------------------------------------------------
__global__ __launch_bounds__(256, 4) void gru_kernel(
    const float* __restrict__ x,     // [BN][128][2]
    const float* __restrict__ wih,   // [384][2]
    const float* __restrict__ whh,   // [384][128]
    const float* __restrict__ bih,   // [384]
    const float* __restrict__ bhh,   // [384]
    float* __restrict__ xh)          // [BN][128]
{
    __shared__ __align__(16) _Float16 h_l[2][16 * 128];  // 8 KB double-buffered
    __shared__ __align__(16) float    fstrip[4][32];     // per-wave {v,ang} for 16 rows

    const int tid  = threadIdx.x;
    const int wv   = tid >> 6;          // wave 0..3 -> cols [32wv, 32wv+32)
    const int lane = tid & 63;
    const int c0   = lane & 15;
    const int rg   = lane >> 4;
    const int rbase = blockIdx.x * 16;

    // ---- whh B-frags -> registers, prescaled ----
    f16x8 wr[2][4], wz[2][4], wn[2][4];
    float w0r[2], w1r[2], bbr[2], w0z[2], w1z[2], bbz[2];
    float w0n[2], w1n[2], bin_[2], bhn_[2];
    #pragma unroll
    for (int ct = 0; ct < 2; ++ct) {
        const int gr = wv * 32 + ct * 16 + c0;   // r-gate row of whh
        const int gz = gr + 128;                 // z
        const int gn = gr + 256;                 // n
        #pragma unroll
        for (int kt = 0; kt < 4; ++kt) {
            int ko = kt * 32 + rg * 8;
            f32x4 r0 = *(const f32x4*)&whh[gr * 128 + ko];
            f32x4 r1 = *(const f32x4*)&whh[gr * 128 + ko + 4];
            f32x4 z0 = *(const f32x4*)&whh[gz * 128 + ko];
            f32x4 z1 = *(const f32x4*)&whh[gz * 128 + ko + 4];
            f32x4 n0 = *(const f32x4*)&whh[gn * 128 + ko];
            f32x4 n1 = *(const f32x4*)&whh[gn * 128 + ko + 4];
            f16x8 fr, fz, fn;
            #pragma unroll
            for (int j = 0; j < 4; ++j) {
                fr[j]     = (_Float16)(r0[j] * LOG2E);
                fr[j + 4] = (_Float16)(r1[j] * LOG2E);
                fz[j]     = (_Float16)(z0[j] * LOG2E);
                fz[j + 4] = (_Float16)(z1[j] * LOG2E);
                fn[j]     = (_Float16)(n0[j] * (2.f * LOG2E));
                fn[j + 4] = (_Float16)(n1[j] * (2.f * LOG2E));
            }
            wr[ct][kt] = fr; wz[ct][kt] = fz; wn[ct][kt] = fn;
        }
        w0r[ct] = wih[gr * 2] * LOG2E;        w1r[ct] = wih[gr * 2 + 1] * LOG2E;
        w0z[ct] = wih[gz * 2] * LOG2E;        w1z[ct] = wih[gz * 2 + 1] * LOG2E;
        w0n[ct] = wih[gn * 2] * 2.f * LOG2E;  w1n[ct] = wih[gn * 2 + 1] * 2.f * LOG2E;
        bbr[ct] = (bih[gr] + bhh[gr]) * LOG2E;
        bbz[ct] = (bih[gz] + bhh[gz]) * LOG2E;
        bin_[ct] = bih[gn] * 2.f * LOG2E;     // outside r*( )
        bhn_[ct] = bhh[gn] * 2.f * LOG2E;     // inside r*( ) -> MFMA acc init
    }

    // ---- zero h buffer 0 (h0 = 0): 16*128 halves = 1024 ints ----
    {
        int* hz = (int*)h_l[0];
        #pragma unroll
        for (int i = 0; i < 4; ++i) hz[i * 256 + tid] = 0;
    }
    __syncthreads();

    // ---- x prologue: c0 <-> row (rbase + c0); lanes 16-63 duplicate ----
    const float2* xp = (const float2*)x;
    const int r0i = rbase + c0;
    float2 xc = xp[r0i * 128 + 0];
    float2 xn = xp[r0i * 128 + 1];
    float vprev = 0.f;

    float h_reg[2][4];   // [ct][i]; row=rg*4+i, col=wv*32+ct*16+c0
    #pragma unroll
    for (int ct = 0; ct < 2; ++ct)
        #pragma unroll
        for (int i = 0; i < 4; ++i) h_reg[ct][i] = 0.f;

    const int swz_a = (c0 & 7) << 3;

    #pragma unroll 1
    for (int t = 0; t < TSTEPS; ++t) {
        // ---- features for row r0i (hardware trans; only lanes<16 publish) ----
        {
            float dx = xn.x - xc.x, dy = xn.y - xc.y;
            float v  = FSQRT(fmaf(dx, dx, dy * dy));
            float pv = (t == 0) ? v : vprev;
            float num = pv * v;
            float den = (pv + 1e-6f) * (v + 1e-6f);
            float cs  = fminf(num * __builtin_amdgcn_rcpf(den), 1.0f);  // in [0,1]
            float an  = acos01(cs);
            vprev = v; xc = xn;
            if (t < TSTEPS - 1) xn = xp[r0i * 128 + t + 2];
            if (lane < 16)
                *(float2*)&fstrip[wv][c0 * 2] = make_float2(v, an);
        }
        // same-wave DS ordering guarantees the strip is visible to the reads below

        const _Float16* hb = h_l[t & 1];
        _Float16*       hw = h_l[(t & 1) ^ 1];

        // features of the 4 rows (rg*4 .. rg*4+3) this lane's C-frags cover
        f32x4 f0 = *(const f32x4*)&fstrip[wv][rg * 8];
        f32x4 f1 = *(const f32x4*)&fstrip[wv][rg * 8 + 4];
        float vv[4] = {f0[0], f0[2], f1[0], f1[2]};
        float aa[4] = {f0[1], f0[3], f1[1], f1[3]};

        // A-frags: h_prev[c0][k], swizzle keyed by row&7 = c0&7
        f16x8 afr[4];
        #pragma unroll
        for (int kt = 0; kt < 4; ++kt) {
            int ko = kt * 32 + rg * 8;
            afr[kt] = *(const f16x8*)&hb[c0 * 128 + (ko ^ swz_a)];
        }

        #pragma unroll
        for (int ct = 0; ct < 2; ++ct) {
            // acc init = input-gate part + folded biases (prescaled)
            f32x4 ar, az, an_;
            float gxn[4];
            #pragma unroll
            for (int i = 0; i < 4; ++i) {
                ar[i]  = fmaf(vv[i], w0r[ct], fmaf(aa[i], w1r[ct], bbr[ct]));
                az[i]  = fmaf(vv[i], w0z[ct], fmaf(aa[i], w1z[ct], bbz[ct]));
                an_[i] = bhn_[ct];
                gxn[i] = fmaf(vv[i], w0n[ct], fmaf(aa[i], w1n[ct], bin_[ct]));
            }
            #pragma unroll
            for (int kt = 0; kt < 4; ++kt) {
                ar  = __builtin_amdgcn_mfma_f32_16x16x32_f16(afr[kt], wr[ct][kt], ar,  0, 0, 0);
                az  = __builtin_amdgcn_mfma_f32_16x16x32_f16(afr[kt], wz[ct][kt], az,  0, 0, 0);
                an_ = __builtin_amdgcn_mfma_f32_16x16x32_f16(afr[kt], wn[ct][kt], an_, 0, 0, 0);
            }
            // r = sigma, z = sigma, nn = tanh(.) -- args prescaled for exp2
            #pragma unroll
            for (int i = 0; i < 4; ++i) {
                float r  = __builtin_amdgcn_rcpf(1.f + EXP2F(-ar[i]));
                float z  = __builtin_amdgcn_rcpf(1.f + EXP2F(-az[i]));
                float sn = fmaf(r, an_[i], gxn[i]);
                float nn = fmaf(-2.f, __builtin_amdgcn_rcpf(1.f + EXP2F(sn)), 1.f);
                float hv = h_reg[ct][i];
                hv = fmaf(z, hv - nn, nn);          // (1-z)*nn + z*h
                h_reg[ct][i] = hv;
                int row = rg * 4 + i;
                int col = wv * 32 + ct * 16 + c0;
                hw[row * 128 + (col ^ ((row & 7) << 3))] = (_Float16)hv;
            }
        }
        __syncthreads();
    }

    // ---- store final h ----
    #pragma unroll
    for (int ct = 0; ct < 2; ++ct)
        #pragma unroll
        for (int i = 0; i < 4; ++i) {
            int r = rbase + rg * 4 + i;
            xh[r * 128 + wv * 32 + ct * 16 + c0] = h_reg[ct][i];
        }
}

// ---------------------------------------------------------------------------
// Kernel 2: collapsed DenseGATConv for node i=0, weff folded in.
// One block per batch b. xh[b] (64KB) is L2-resident; reads are coalesced.
// ---------------------------------------------------------------------------
__global__ __launch_bounds__(256) void gat_kernel(
    const float* __restrict__ xh,      // [B*N][128]
    const float* __restrict__ gat_w,   // [512][128]  (= [h][c][f])
    const float* __restrict__ att_src, // [4][128]
    const float* __restrict__ att_dst, // [4][128]
    const float* __restrict__ gbias,   // [128]
    float* __restrict__ out)           // [B][128]
{
    __shared__ __align__(16) float wse_l[512];    // [h][f]
    __shared__ __align__(16) float wde_l[512];    // [h][f]
    __shared__ float asrc[512];                   // [j][h]
    __shared__ float wgt[512];                    // [j][h]
    __shared__ __align__(16) float m_l[512];      // [h][f]
    __shared__ float asd[4];

    const int b = blockIdx.x, tid = threadIdx.x;
    const float* xb = xh + b * 16384;

    // phase 0: ws_eff[h][f] = sum_c att[h][c] * W[h][c][f]  (coalesced over f)
    #pragma unroll
    for (int p2 = 0; p2 < 2; ++p2) {
        int p = p2 * 256 + tid;
        int h = p >> 7, f = p & 127;
        float ss = 0.f, dd = 0.f;
        for (int c = 0; c < 128; ++c) {
            float w = gat_w[(h * 128 + c) * 128 + f];
            ss = fmaf(att_src[h * 128 + c], w, ss);
            dd = fmaf(att_dst[h * 128 + c], w, dd);
        }
        wse_l[p] = ss;
        wde_l[p] = dd;
    }
    __syncthreads();

    // a_src[j][h] = xh[j] . wse[h]   (4 lanes share each xh 16B read)
    #pragma unroll
    for (int p2 = 0; p2 < 2; ++p2) {
        int p = p2 * 256 + tid;
        int j = p >> 2, h = p & 3;
        const float* wrp = wse_l + h * 128;
        const float* xr  = xb + j * 128;
        float acc = 0.f;
        for (int f = 0; f < 128; f += 4) {
            f32x4 xv  = *(const f32x4*)&xr[f];
            f32x4 wvv = *(const f32x4*)&wrp[f];
            acc += xv[0] * wvv[0] + xv[1] * wvv[1] + xv[2] * wvv[2] + xv[3] * wvv[3];
        }
        asrc[j * 4 + h] = acc;
    }
    if (tid < 4) {     // a_dst at node 0
        const float* wrp = wde_l + tid * 128;
        float acc = 0.f;
        for (int f = 0; f < 128; f += 4) {
            f32x4 xv  = *(const f32x4*)&xb[f];
            f32x4 wvv = *(const f32x4*)&wrp[f];
            acc += xv[0] * wvv[0] + xv[1] * wvv[1] + xv[2] * wvv[2] + xv[3] * wvv[3];
        }
        asd[tid] = acc;
    }
    __syncthreads();

    // per-head softmax over j (wave h handles head h; lanes hold j and j+64)
    {
        int h = tid >> 6, j = tid & 63;
        float a0 = asrc[j * 4 + h] + asd[h];
        float a1 = asrc[(j + 64) * 4 + h] + asd[h];
        float e0 = a0 > 0.f ? a0 : 0.2f * a0;     // leaky_relu 0.2
        float e1 = a1 > 0.f ? a1 : 0.2f * a1;
        float mx = fmaxf(e0, e1);
        #pragma unroll
        for (int m = 32; m >= 1; m >>= 1) mx = fmaxf(mx, __shfl_xor(mx, m, 64));
        float p0 = __expf(e0 - mx), p1 = __expf(e1 - mx);
        float s = p0 + p1;
        #pragma unroll
        for (int m = 32; m >= 1; m >>= 1) s += __shfl_xor(s, m, 64);
        float inv = 1.f / s;
        wgt[j * 4 + h] = p0 * inv;
        wgt[(j + 64) * 4 + h] = p1 * inv;
    }
    __syncthreads();

    // m[h][f] = sum_j wgt[j][h] * xh[j][f]   (lane f consecutive -> coalesced)
    #pragma unroll
    for (int p2 = 0; p2 < 2; ++p2) {
        int p = p2 * 256 + tid;
        int h = p >> 7, f = p & 127;
        float acc = 0.f;
        for (int j = 0; j < 128; ++j)
            acc = fmaf(wgt[j * 4 + h], xb[j * 128 + f], acc);
        m_l[h * 128 + f] = acc;
    }
    __syncthreads();

    // out[b][c] = 0.25 * sum_h sum_f m[h][f] * W[h][c][f] + bias[c]
    if (tid < 128) {
        int c = tid;
        float acc = 0.f;
        #pragma unroll
        for (int h = 0; h < 4; ++h) {
            const float* wrp = gat_w + (h * 128 + c) * 128;
            const float* mr  = m_l + h * 128;
            for (int f = 0; f < 128; f += 4) {
                f32x4 wvv = *(const f32x4*)&wrp[f];
                f32x4 mv  = *(const f32x4*)&mr[f];
                acc += wvv[0] * mv[0] + wvv[1] * mv[1] + wvv[2] * mv[2] + wvv[3] * mv[3];
            }
        }
        out[b * 128 + c] = 0.25f * acc + gbias[c];
    }
}

// ---------------------------------------------------------------------------
extern "C" void kernel_launch(void* const* d_in, const int* in_sizes, int n_in,
                              void* d_out, int out_size, void* d_ws, size_t ws_size,
                              hipStream_t stream) {
    const float* x       = (const float*)d_in[0];
    const float* wih     = (const float*)d_in[1];
    const float* whh     = (const float*)d_in[2];
    const float* bih     = (const float*)d_in[3];
    const float* bhh     = (const float*)d_in[4];
    const float* gat_w   = (const float*)d_in[5];
    const float* att_src = (const float*)d_in[6];
    const float* att_dst = (const float*)d_in[7];
    const float* gbias   = (const float*)d_in[8];
    float* outp = (float*)d_out;

    float* xh = (float*)d_ws;              // 16384*128 f32 (8.39 MB)

    gru_kernel<<<1024, 256, 0, stream>>>(x, wih, whh, bih, bhh, xh);
    gat_kernel<<<128, 256, 0, stream>>>(xh, gat_w, att_src, att_dst, gbias, outp);
}

// Round 7
// 420.419 us; speedup vs baseline: 5.2703x; 5.2703x over previous
//
#include <hip/hip_runtime.h>

// B=128, N=128, L=128 -> BN=16384 rows, T=127 steps, HID=CD=128, HEADS=4.
// v6 = v5 with __launch_bounds__(256,2): v5's (256,4) forced VGPR=64 and spilled
// the register-resident whh B-frags to scratch (FETCH 7.7GB, HBM-bound, 2137us).
// v4 proved (256,2) holds the live set at VGPR=128 spill-free (FETCH 11MB).
// Keeps v5's hardware transcendentals (v_exp/v_sqrt/v_rcp + acos poly).
// (Resubmission: round-6 bench never acquired a GPU.)

#define BN_TOT 16384
#define TSTEPS 127
#define LOG2E  1.44269504f

#ifndef __has_builtin
#define __has_builtin(x) 0
#endif
#if __has_builtin(__builtin_amdgcn_exp2f)
#define EXP2F(x) __builtin_amdgcn_exp2f(x)
#else
#define EXP2F(x) exp2f(x)
#endif
#if __has_builtin(__builtin_amdgcn_sqrtf)
#define FSQRT(x) __builtin_amdgcn_sqrtf(x)
#else
#define FSQRT(x) sqrtf(x)
#endif

typedef _Float16 f16x8 __attribute__((ext_vector_type(8)));
typedef float    f32x4 __attribute__((ext_vector_type(4)));

// acos for x in [0,1]: Abramowitz-Stegun 4.4.45, max err ~6.7e-5 rad.
__device__ __forceinline__ float acos01(float x) {
    float s = FSQRT(1.0f - x);
    float p = fmaf(x, -0.0187293f, 0.0742610f);
    p = fmaf(x, p, -0.2121144f);
    p = fmaf(x, p, 1.5707288f);
    return s * p;
}

// ---------------------------------------------------------------------------
// Kernel 1: fused features + GRU.
// 1024 blocks x 256 thr (4 waves). Block owns 16 rows; wave wv owns cols
// [32wv, 32wv+32). whh B-frags register-resident, prescaled by log2e (r,z) /
// 2*log2e (n) so each gate nonlinearity is v_exp + v_rcp. h double-buffered in
// LDS fp16, XOR swizzle (col ^ ((row&7)<<3)), ONE barrier per step.
// MFMA 16x16x32 f16: A lane l -> row=l&15, k=(l>>4)*8+j ; B lane l -> col=l&15,
// same k ; C lane l reg i -> row=(l>>4)*4+i, col=l&15.
// ---------------------------------------------------------------------------
__global__ __launch_bounds__(256, 2) void gru_kernel(
    const float* __restrict__ x,     // [BN][128][2]
    const float* __restrict__ wih,   // [384][2]
    const float* __restrict__ whh,   // [384][128]
    const float* __restrict__ bih,   // [384]
    const float* __restrict__ bhh,   // [384]
    float* __restrict__ xh)          // [BN][128]
{
    __shared__ __align__(16) _Float16 h_l[2][16 * 128];  // 8 KB double-buffered
    __shared__ __align__(16) float    fstrip[4][32];     // per-wave {v,ang} for 16 rows

    const int tid  = threadIdx.x;
    const int wv   = tid >> 6;          // wave 0..3 -> cols [32wv, 32wv+32)
    const int lane = tid & 63;
    const int c0   = lane & 15;
    const int rg   = lane >> 4;
    const int rbase = blockIdx.x * 16;

    // ---- whh B-frags -> registers, prescaled ----
    f16x8 wr[2][4], wz[2][4], wn[2][4];
    float w0r[2], w1r[2], bbr[2], w0z[2], w1z[2], bbz[2];
    float w0n[2], w1n[2], bin_[2], bhn_[2];
    #pragma unroll
    for (int ct = 0; ct < 2; ++ct) {
        const int gr = wv * 32 + ct * 16 + c0;   // r-gate row of whh
        const int gz = gr + 128;                 // z
        const int gn = gr + 256;                 // n
        #pragma unroll
        for (int kt = 0; kt < 4; ++kt) {
            int ko = kt * 32 + rg * 8;
            f32x4 r0 = *(const f32x4*)&whh[gr * 128 + ko];
            f32x4 r1 = *(const f32x4*)&whh[gr * 128 + ko + 4];
            f32x4 z0 = *(const f32x4*)&whh[gz * 128 + ko];
            f32x4 z1 = *(const f32x4*)&whh[gz * 128 + ko + 4];
            f32x4 n0 = *(const f32x4*)&whh[gn * 128 + ko];
            f32x4 n1 = *(const f32x4*)&whh[gn * 128 + ko + 4];
            f16x8 fr, fz, fn;
            #pragma unroll
            for (int j = 0; j < 4; ++j) {
                fr[j]     = (_Float16)(r0[j] * LOG2E);
                fr[j + 4] = (_Float16)(r1[j] * LOG2E);
                fz[j]     = (_Float16)(z0[j] * LOG2E);
                fz[j + 4] = (_Float16)(z1[j] * LOG2E);
                fn[j]     = (_Float16)(n0[j] * (2.f * LOG2E));
                fn[j + 4] = (_Float16)(n1[j] * (2.f * LOG2E));
            }
            wr[ct][kt] = fr; wz[ct][kt] = fz; wn[ct][kt] = fn;
        }
        w0r[ct] = wih[gr * 2] * LOG2E;        w1r[ct] = wih[gr * 2 + 1] * LOG2E;
        w0z[ct] = wih[gz * 2] * LOG2E;        w1z[ct] = wih[gz * 2 + 1] * LOG2E;
        w0n[ct] = wih[gn * 2] * 2.f * LOG2E;  w1n[ct] = wih[gn * 2 + 1] * 2.f * LOG2E;
        bbr[ct] = (bih[gr] + bhh[gr]) * LOG2E;
        bbz[ct] = (bih[gz] + bhh[gz]) * LOG2E;
        bin_[ct] = bih[gn] * 2.f * LOG2E;     // outside r*( )
        bhn_[ct] = bhh[gn] * 2.f * LOG2E;     // inside r*( ) -> MFMA acc init
    }

    // ---- zero h buffer 0 (h0 = 0): 16*128 halves = 1024 ints ----
    {
        int* hz = (int*)h_l[0];
        #pragma unroll
        for (int i = 0; i < 4; ++i) hz[i * 256 + tid] = 0;
    }
    __syncthreads();

    // ---- x prologue: c0 <-> row (rbase + c0); lanes 16-63 duplicate ----
    const float2* xp = (const float2*)x;
    const int r0i = rbase + c0;
    float2 xc = xp[r0i * 128 + 0];
    float2 xn = xp[r0i * 128 + 1];
    float vprev = 0.f;

    float h_reg[2][4];   // [ct][i]; row=rg*4+i, col=wv*32+ct*16+c0
    #pragma unroll
    for (int ct = 0; ct < 2; ++ct)
        #pragma unroll
        for (int i = 0; i < 4; ++i) h_reg[ct][i] = 0.f;

    const int swz_a = (c0 & 7) << 3;

    #pragma unroll 1
    for (int t = 0; t < TSTEPS; ++t) {
        // ---- features for row r0i (hardware trans; only lanes<16 publish) ----
        {
            float dx = xn.x - xc.x, dy = xn.y - xc.y;
            float v  = FSQRT(fmaf(dx, dx, dy * dy));
            float pv = (t == 0) ? v : vprev;
            float num = pv * v;
            float den = (pv + 1e-6f) * (v + 1e-6f);
            float cs  = fminf(num * __builtin_amdgcn_rcpf(den), 1.0f);  // in [0,1]
            float an  = acos01(cs);
            vprev = v; xc = xn;
            if (t < TSTEPS - 1) xn = xp[r0i * 128 + t + 2];
            if (lane < 16)
                *(float2*)&fstrip[wv][c0 * 2] = make_float2(v, an);
        }
        // same-wave DS ordering makes the strip visible to this wave's reads below

        const _Float16* hb = h_l[t & 1];
        _Float16*       hw = h_l[(t & 1) ^ 1];

        // features of the 4 rows (rg*4 .. rg*4+3) this lane's C-frags cover
        f32x4 f0 = *(const f32x4*)&fstrip[wv][rg * 8];
        f32x4 f1 = *(const f32x4*)&fstrip[wv][rg * 8 + 4];
        float vv[4] = {f0[0], f0[2], f1[0], f1[2]};
        float aa[4] = {f0[1], f0[3], f1[1], f1[3]};

        // A-frags: h_prev[c0][k], swizzle keyed by row&7 = c0&7
        f16x8 afr[4];
        #pragma unroll
        for (int kt = 0; kt < 4; ++kt) {
            int ko = kt * 32 + rg * 8;
            afr[kt] = *(const f16x8*)&hb[c0 * 128 + (ko ^ swz_a)];
        }

        #pragma unroll
        for (int ct = 0; ct < 2; ++ct) {
            // acc init = input-gate part + folded biases (prescaled)
            f32x4 ar, az, an_;
            float gxn[4];
            #pragma unroll
            for (int i = 0; i < 4; ++i) {
                ar[i]  = fmaf(vv[i], w0r[ct], fmaf(aa[i], w1r[ct], bbr[ct]));
                az[i]  = fmaf(vv[i], w0z[ct], fmaf(aa[i], w1z[ct], bbz[ct]));
                an_[i] = bhn_[ct];
                gxn[i] = fmaf(vv[i], w0n[ct], fmaf(aa[i], w1n[ct], bin_[ct]));
            }
            #pragma unroll
            for (int kt = 0; kt < 4; ++kt) {
                ar  = __builtin_amdgcn_mfma_f32_16x16x32_f16(afr[kt], wr[ct][kt], ar,  0, 0, 0);
                az  = __builtin_amdgcn_mfma_f32_16x16x32_f16(afr[kt], wz[ct][kt], az,  0, 0, 0);
                an_ = __builtin_amdgcn_mfma_f32_16x16x32_f16(afr[kt], wn[ct][kt], an_, 0, 0, 0);
            }
            // r = sigma, z = sigma, nn = tanh(.) -- args prescaled for exp2
            #pragma unroll
            for (int i = 0; i < 4; ++i) {
                float r  = __builtin_amdgcn_rcpf(1.f + EXP2F(-ar[i]));
                float z  = __builtin_amdgcn_rcpf(1.f + EXP2F(-az[i]));
                float sn = fmaf(r, an_[i], gxn[i]);
                float nn = fmaf(-2.f, __builtin_amdgcn_rcpf(1.f + EXP2F(sn)), 1.f);
                float hv = h_reg[ct][i];
                hv = fmaf(z, hv - nn, nn);          // (1-z)*nn + z*h
                h_reg[ct][i] = hv;
                int row = rg * 4 + i;
                int col = wv * 32 + ct * 16 + c0;
                hw[row * 128 + (col ^ ((row & 7) << 3))] = (_Float16)hv;
            }
        }
        __syncthreads();
    }

    // ---- store final h ----
    #pragma unroll
    for (int ct = 0; ct < 2; ++ct)
        #pragma unroll
        for (int i = 0; i < 4; ++i) {
            int r = rbase + rg * 4 + i;
            xh[r * 128 + wv * 32 + ct * 16 + c0] = h_reg[ct][i];
        }
}

// ---------------------------------------------------------------------------
// Kernel 2: collapsed DenseGATConv for node i=0, weff folded in.
// One block per batch b. xh[b] (64KB) is L2-resident; reads are coalesced.
// ---------------------------------------------------------------------------
__global__ __launch_bounds__(256) void gat_kernel(
    const float* __restrict__ xh,      // [B*N][128]
    const float* __restrict__ gat_w,   // [512][128]  (= [h][c][f])
    const float* __restrict__ att_src, // [4][128]
    const float* __restrict__ att_dst, // [4][128]
    const float* __restrict__ gbias,   // [128]
    float* __restrict__ out)           // [B][128]
{
    __shared__ __align__(16) float wse_l[512];    // [h][f]
    __shared__ __align__(16) float wde_l[512];    // [h][f]
    __shared__ float asrc[512];                   // [j][h]
    __shared__ float wgt[512];                    // [j][h]
    __shared__ __align__(16) float m_l[512];      // [h][f]
    __shared__ float asd[4];

    const int b = blockIdx.x, tid = threadIdx.x;
    const float* xb = xh + b * 16384;

    // phase 0: ws_eff[h][f] = sum_c att[h][c] * W[h][c][f]  (coalesced over f)
    #pragma unroll
    for (int p2 = 0; p2 < 2; ++p2) {
        int p = p2 * 256 + tid;
        int h = p >> 7, f = p & 127;
        float ss = 0.f, dd = 0.f;
        for (int c = 0; c < 128; ++c) {
            float w = gat_w[(h * 128 + c) * 128 + f];
            ss = fmaf(att_src[h * 128 + c], w, ss);
            dd = fmaf(att_dst[h * 128 + c], w, dd);
        }
        wse_l[p] = ss;
        wde_l[p] = dd;
    }
    __syncthreads();

    // a_src[j][h] = xh[j] . wse[h]   (4 lanes share each xh 16B read)
    #pragma unroll
    for (int p2 = 0; p2 < 2; ++p2) {
        int p = p2 * 256 + tid;
        int j = p >> 2, h = p & 3;
        const float* wrp = wse_l + h * 128;
        const float* xr  = xb + j * 128;
        float acc = 0.f;
        for (int f = 0; f < 128; f += 4) {
            f32x4 xv  = *(const f32x4*)&xr[f];
            f32x4 wvv = *(const f32x4*)&wrp[f];
            acc += xv[0] * wvv[0] + xv[1] * wvv[1] + xv[2] * wvv[2] + xv[3] * wvv[3];
        }
        asrc[j * 4 + h] = acc;
    }
    if (tid < 4) {     // a_dst at node 0
        const float* wrp = wde_l + tid * 128;
        float acc = 0.f;
        for (int f = 0; f < 128; f += 4) {
            f32x4 xv  = *(const f32x4*)&xb[f];
            f32x4 wvv = *(const f32x4*)&wrp[f];
            acc += xv[0] * wvv[0] + xv[1] * wvv[1] + xv[2] * wvv[2] + xv[3] * wvv[3];
        }
        asd[tid] = acc;
    }
    __syncthreads();

    // per-head softmax over j (wave h handles head h; lanes hold j and j+64)
    {
        int h = tid >> 6, j = tid & 63;
        float a0 = asrc[j * 4 + h] + asd[h];
        float a1 = asrc[(j + 64) * 4 + h] + asd[h];
        float e0 = a0 > 0.f ? a0 : 0.2f * a0;     // leaky_relu 0.2
        float e1 = a1 > 0.f ? a1 : 0.2f * a1;
        float mx = fmaxf(e0, e1);
        #pragma unroll
        for (int m = 32; m >= 1; m >>= 1) mx = fmaxf(mx, __shfl_xor(mx, m, 64));
        float p0 = __expf(e0 - mx), p1 = __expf(e1 - mx);
        float s = p0 + p1;
        #pragma unroll
        for (int m = 32; m >= 1; m >>= 1) s += __shfl_xor(s, m, 64);
        float inv = 1.f / s;
        wgt[j * 4 + h] = p0 * inv;
        wgt[(j + 64) * 4 + h] = p1 * inv;
    }
    __syncthreads();

    // m[h][f] = sum_j wgt[j][h] * xh[j][f]   (lane f consecutive -> coalesced)
    #pragma unroll
    for (int p2 = 0; p2 < 2; ++p2) {
        int p = p2 * 256 + tid;
        int h = p >> 7, f = p & 127;
        float acc = 0.f;
        for (int j = 0; j < 128; ++j)
            acc = fmaf(wgt[j * 4 + h], xb[j * 128 + f], acc);
        m_l[h * 128 + f] = acc;
    }
    __syncthreads();

    // out[b][c] = 0.25 * sum_h sum_f m[h][f] * W[h][c][f] + bias[c]
    if (tid < 128) {
        int c = tid;
        float acc = 0.f;
        #pragma unroll
        for (int h = 0; h < 4; ++h) {
            const float* wrp = gat_w + (h * 128 + c) * 128;
            const float* mr  = m_l + h * 128;
            for (int f = 0; f < 128; f += 4) {
                f32x4 wvv = *(const f32x4*)&wrp[f];
                f32x4 mv  = *(const f32x4*)&mr[f];
                acc += wvv[0] * mv[0] + wvv[1] * mv[1] + wvv[2] * mv[2] + wvv[3] * mv[3];
            }
        }
        out[b * 128 + c] = 0.25f * acc + gbias[c];
    }
}

// ---------------------------------------------------------------------------
extern "C" void kernel_launch(void* const* d_in, const int* in_sizes, int n_in,
                              void* d_out, int out_size, void* d_ws, size_t ws_size,
                              hipStream_t stream) {
    const float* x       = (const float*)d_in[0];
    const float* wih     = (const float*)d_in[1];
    const float* whh     = (const float*)d_in[2];
    const float* bih     = (const float*)d_in[3];
    const float* bhh     = (const float*)d_in[4];
    const float* gat_w   = (const float*)d_in[5];
    const float* att_src = (const float*)d_in[6];
    const float* att_dst = (const float*)d_in[7];
    const float* gbias   = (const float*)d_in[8];
    float* outp = (float*)d_out;

    float* xh = (float*)d_ws;              // 16384*128 f32 (8.39 MB)

    gru_kernel<<<1024, 256, 0, stream>>>(x, wih, whh, bih, bhh, xh);
    gat_kernel<<<128, 256, 0, stream>>>(xh, gat_w, att_src, att_dst, gbias, outp);
}

// Round 8
// 408.092 us; speedup vs baseline: 5.4294x; 1.0302x over previous
//
#include <hip/hip_runtime.h>

// B=128, N=128, L=128 -> BN=16384 rows, T=127 steps, HID=CD=128, HEADS=4.
// v7 = v6 + feature precompute into LDS. v6 post-mortem: per-step __syncthreads
// drains vmcnt(0), so the in-loop x prefetch put ~300-900cy of HBM latency on the
// recurrence critical path every step (wall 7143 cy/step vs ~1900 issue-bound).
// Now: two parallel phases fill f_lds[t][row]={v,ang} (features are t-parallel),
// and the 127-step loop has ZERO global loads / sqrt / acos -- barriers only wait
// on LDS. Gate math keeps v_exp/v_rcp with log2e-prescaled weights.

#define BN_TOT 16384
#define TSTEPS 127
#define LOG2E  1.44269504f

#ifndef __has_builtin
#define __has_builtin(x) 0
#endif
#if __has_builtin(__builtin_amdgcn_exp2f)
#define EXP2F(x) __builtin_amdgcn_exp2f(x)
#else
#define EXP2F(x) exp2f(x)
#endif
#if __has_builtin(__builtin_amdgcn_sqrtf)
#define FSQRT(x) __builtin_amdgcn_sqrtf(x)
#else
#define FSQRT(x) sqrtf(x)
#endif

typedef _Float16 f16x8 __attribute__((ext_vector_type(8)));
typedef float    f32x4 __attribute__((ext_vector_type(4)));

// acos for x in [0,1]: Abramowitz-Stegun 4.4.45, max err ~6.7e-5 rad.
__device__ __forceinline__ float acos01(float x) {
    float s = FSQRT(1.0f - x);
    float p = fmaf(x, -0.0187293f, 0.0742610f);
    p = fmaf(x, p, -0.2121144f);
    p = fmaf(x, p, 1.5707288f);
    return s * p;
}

// ---------------------------------------------------------------------------
// Kernel 1: fused features + GRU.
// 1024 blocks x 256 thr (4 waves). Block owns 16 rows; wave wv owns cols
// [32wv, 32wv+32). whh B-frags register-resident, prescaled by log2e (r,z) /
// 2*log2e (n). h double-buffered in LDS fp16, XOR swizzle (col ^ ((row&7)<<3)),
// ONE barrier per step (LDS-only drain).
// MFMA 16x16x32 f16: A lane l -> row=l&15, k=(l>>4)*8+j ; B lane l -> col=l&15,
// same k ; C lane l reg i -> row=(l>>4)*4+i, col=l&15.
// ---------------------------------------------------------------------------
__global__ __launch_bounds__(256, 2) void gru_kernel(
    const float* __restrict__ x,     // [BN][128][2]
    const float* __restrict__ wih,   // [384][2]
    const float* __restrict__ whh,   // [384][128]
    const float* __restrict__ bih,   // [384]
    const float* __restrict__ bhh,   // [384]
    float* __restrict__ xh)          // [BN][128]
{
    __shared__ __align__(16) _Float16 h_l[2][16 * 128];  // 8 KB double-buffered
    __shared__ __align__(16) float2   f_lds[128][16];    // 16 KB: [t][row] = {v, ang}

    const int tid  = threadIdx.x;
    const int wv   = tid >> 6;          // wave 0..3 -> cols [32wv, 32wv+32)
    const int lane = tid & 63;
    const int c0   = lane & 15;
    const int rg   = lane >> 4;
    const int rbase = blockIdx.x * 16;

    // ---- whh B-frags -> registers, prescaled ----
    f16x8 wr[2][4], wz[2][4], wn[2][4];
    float w0r[2], w1r[2], bbr[2], w0z[2], w1z[2], bbz[2];
    float w0n[2], w1n[2], bin_[2], bhn_[2];
    #pragma unroll
    for (int ct = 0; ct < 2; ++ct) {
        const int gr = wv * 32 + ct * 16 + c0;   // r-gate row of whh
        const int gz = gr + 128;                 // z
        const int gn = gr + 256;                 // n
        #pragma unroll
        for (int kt = 0; kt < 4; ++kt) {
            int ko = kt * 32 + rg * 8;
            f32x4 r0 = *(const f32x4*)&whh[gr * 128 + ko];
            f32x4 r1 = *(const f32x4*)&whh[gr * 128 + ko + 4];
            f32x4 z0 = *(const f32x4*)&whh[gz * 128 + ko];
            f32x4 z1 = *(const f32x4*)&whh[gz * 128 + ko + 4];
            f32x4 n0 = *(const f32x4*)&whh[gn * 128 + ko];
            f32x4 n1 = *(const f32x4*)&whh[gn * 128 + ko + 4];
            f16x8 fr, fz, fn;
            #pragma unroll
            for (int j = 0; j < 4; ++j) {
                fr[j]     = (_Float16)(r0[j] * LOG2E);
                fr[j + 4] = (_Float16)(r1[j] * LOG2E);
                fz[j]     = (_Float16)(z0[j] * LOG2E);
                fz[j + 4] = (_Float16)(z1[j] * LOG2E);
                fn[j]     = (_Float16)(n0[j] * (2.f * LOG2E));
                fn[j + 4] = (_Float16)(n1[j] * (2.f * LOG2E));
            }
            wr[ct][kt] = fr; wz[ct][kt] = fz; wn[ct][kt] = fn;
        }
        w0r[ct] = wih[gr * 2] * LOG2E;        w1r[ct] = wih[gr * 2 + 1] * LOG2E;
        w0z[ct] = wih[gz * 2] * LOG2E;        w1z[ct] = wih[gz * 2 + 1] * LOG2E;
        w0n[ct] = wih[gn * 2] * 2.f * LOG2E;  w1n[ct] = wih[gn * 2 + 1] * 2.f * LOG2E;
        bbr[ct] = (bih[gr] + bhh[gr]) * LOG2E;
        bbz[ct] = (bih[gz] + bhh[gz]) * LOG2E;
        bin_[ct] = bih[gn] * 2.f * LOG2E;     // outside r*( )
        bhn_[ct] = bhh[gn] * 2.f * LOG2E;     // inside r*( ) -> MFMA acc init
    }

    // ---- phase 1: speeds v[row][t] = |x[t+1]-x[t]|, t-parallel, coalesced ----
    const float2* xp = (const float2*)x;
    #pragma unroll
    for (int i = 0; i < 8; ++i) {
        int p = i * 256 + tid;          // 0..2047
        int row = p >> 7, t = p & 127;
        if (t < TSTEPS) {
            float2 a = xp[(rbase + row) * 128 + t];
            float2 b = xp[(rbase + row) * 128 + t + 1];
            float dx = b.x - a.x, dy = b.y - a.y;
            f_lds[t][row].x = FSQRT(fmaf(dx, dx, dy * dy));
        }
    }
    // ---- zero h buffer 0 (h0 = 0): 16*128 halves = 1024 ints ----
    {
        int* hz = (int*)h_l[0];
        #pragma unroll
        for (int i = 0; i < 4; ++i) hz[i * 256 + tid] = 0;
    }
    __syncthreads();

    // ---- phase 2: angles (reads .x of t and t-1, writes .y: no race) ----
    #pragma unroll
    for (int i = 0; i < 8; ++i) {
        int p = i * 256 + tid;
        int row = p >> 7, t = p & 127;
        if (t < TSTEPS) {
            float v  = f_lds[t][row].x;
            float pv = f_lds[(t == 0) ? 0 : (t - 1)][row].x;
            float num = pv * v;
            float den = (pv + 1e-6f) * (v + 1e-6f);
            float cs  = fminf(num * __builtin_amdgcn_rcpf(den), 1.0f);  // in [0,1]
            f_lds[t][row].y = acos01(cs);
        }
    }
    __syncthreads();

    float h_reg[2][4];   // [ct][i]; row=rg*4+i, col=wv*32+ct*16+c0
    #pragma unroll
    for (int ct = 0; ct < 2; ++ct)
        #pragma unroll
        for (int i = 0; i < 4; ++i) h_reg[ct][i] = 0.f;

    const int swz_a = (c0 & 7) << 3;

    #pragma unroll 1
    for (int t = 0; t < TSTEPS; ++t) {
        const _Float16* hb = h_l[t & 1];
        _Float16*       hw = h_l[(t & 1) ^ 1];

        // features of the 4 rows (rg*4 .. rg*4+3): 2 x ds_read_b128, broadcast
        const f32x4* fb = (const f32x4*)&f_lds[t][rg * 4];
        f32x4 f0 = fb[0];
        f32x4 f1 = fb[1];
        float vv[4] = {f0[0], f0[2], f1[0], f1[2]};
        float aa[4] = {f0[1], f0[3], f1[1], f1[3]};

        // A-frags: h_prev[c0][k], swizzle keyed by row&7 = c0&7
        f16x8 afr[4];
        #pragma unroll
        for (int kt = 0; kt < 4; ++kt) {
            int ko = kt * 32 + rg * 8;
            afr[kt] = *(const f16x8*)&hb[c0 * 128 + (ko ^ swz_a)];
        }

        #pragma unroll
        for (int ct = 0; ct < 2; ++ct) {
            // acc init = input-gate part + folded biases (prescaled)
            f32x4 ar, az, an_;
            float gxn[4];
            #pragma unroll
            for (int i = 0; i < 4; ++i) {
                ar[i]  = fmaf(vv[i], w0r[ct], fmaf(aa[i], w1r[ct], bbr[ct]));
                az[i]  = fmaf(vv[i], w0z[ct], fmaf(aa[i], w1z[ct], bbz[ct]));
                an_[i] = bhn_[ct];
                gxn[i] = fmaf(vv[i], w0n[ct], fmaf(aa[i], w1n[ct], bin_[ct]));
            }
            #pragma unroll
            for (int kt = 0; kt < 4; ++kt) {
                ar  = __builtin_amdgcn_mfma_f32_16x16x32_f16(afr[kt], wr[ct][kt], ar,  0, 0, 0);
                az  = __builtin_amdgcn_mfma_f32_16x16x32_f16(afr[kt], wz[ct][kt], az,  0, 0, 0);
                an_ = __builtin_amdgcn_mfma_f32_16x16x32_f16(afr[kt], wn[ct][kt], an_, 0, 0, 0);
            }
            // r = sigma, z = sigma, nn = tanh(.) -- args prescaled for exp2
            #pragma unroll
            for (int i = 0; i < 4; ++i) {
                float r  = __builtin_amdgcn_rcpf(1.f + EXP2F(-ar[i]));
                float z  = __builtin_amdgcn_rcpf(1.f + EXP2F(-az[i]));
                float sn = fmaf(r, an_[i], gxn[i]);
                float nn = fmaf(-2.f, __builtin_amdgcn_rcpf(1.f + EXP2F(sn)), 1.f);
                float hv = h_reg[ct][i];
                hv = fmaf(z, hv - nn, nn);          // (1-z)*nn + z*h
                h_reg[ct][i] = hv;
                int row = rg * 4 + i;
                int col = wv * 32 + ct * 16 + c0;
                hw[row * 128 + (col ^ ((row & 7) << 3))] = (_Float16)hv;
            }
        }
        __syncthreads();
    }

    // ---- store final h ----
    #pragma unroll
    for (int ct = 0; ct < 2; ++ct)
        #pragma unroll
        for (int i = 0; i < 4; ++i) {
            int r = rbase + rg * 4 + i;
            xh[r * 128 + wv * 32 + ct * 16 + c0] = h_reg[ct][i];
        }
}

// ---------------------------------------------------------------------------
// Kernel 2: collapsed DenseGATConv for node i=0, weff folded in.
// One block per batch b. xh[b] (64KB) is L2-resident; reads are coalesced.
// ---------------------------------------------------------------------------
__global__ __launch_bounds__(256) void gat_kernel(
    const float* __restrict__ xh,      // [B*N][128]
    const float* __restrict__ gat_w,   // [512][128]  (= [h][c][f])
    const float* __restrict__ att_src, // [4][128]
    const float* __restrict__ att_dst, // [4][128]
    const float* __restrict__ gbias,   // [128]
    float* __restrict__ out)           // [B][128]
{
    __shared__ __align__(16) float wse_l[512];    // [h][f]
    __shared__ __align__(16) float wde_l[512];    // [h][f]
    __shared__ float asrc[512];                   // [j][h]
    __shared__ float wgt[512];                    // [j][h]
    __shared__ __align__(16) float m_l[512];      // [h][f]
    __shared__ float asd[4];

    const int b = blockIdx.x, tid = threadIdx.x;
    const float* xb = xh + b * 16384;

    // phase 0: ws_eff[h][f] = sum_c att[h][c] * W[h][c][f]  (coalesced over f)
    #pragma unroll
    for (int p2 = 0; p2 < 2; ++p2) {
        int p = p2 * 256 + tid;
        int h = p >> 7, f = p & 127;
        float ss = 0.f, dd = 0.f;
        for (int c = 0; c < 128; ++c) {
            float w = gat_w[(h * 128 + c) * 128 + f];
            ss = fmaf(att_src[h * 128 + c], w, ss);
            dd = fmaf(att_dst[h * 128 + c], w, dd);
        }
        wse_l[p] = ss;
        wde_l[p] = dd;
    }
    __syncthreads();

    // a_src[j][h] = xh[j] . wse[h]   (4 lanes share each xh 16B read)
    #pragma unroll
    for (int p2 = 0; p2 < 2; ++p2) {
        int p = p2 * 256 + tid;
        int j = p >> 2, h = p & 3;
        const float* wrp = wse_l + h * 128;
        const float* xr  = xb + j * 128;
        float acc = 0.f;
        for (int f = 0; f < 128; f += 4) {
            f32x4 xv  = *(const f32x4*)&xr[f];
            f32x4 wvv = *(const f32x4*)&wrp[f];
            acc += xv[0] * wvv[0] + xv[1] * wvv[1] + xv[2] * wvv[2] + xv[3] * wvv[3];
        }
        asrc[j * 4 + h] = acc;
    }
    if (tid < 4) {     // a_dst at node 0
        const float* wrp = wde_l + tid * 128;
        float acc = 0.f;
        for (int f = 0; f < 128; f += 4) {
            f32x4 xv  = *(const f32x4*)&xb[f];
            f32x4 wvv = *(const f32x4*)&wrp[f];
            acc += xv[0] * wvv[0] + xv[1] * wvv[1] + xv[2] * wvv[2] + xv[3] * wvv[3];
        }
        asd[tid] = acc;
    }
    __syncthreads();

    // per-head softmax over j (wave h handles head h; lanes hold j and j+64)
    {
        int h = tid >> 6, j = tid & 63;
        float a0 = asrc[j * 4 + h] + asd[h];
        float a1 = asrc[(j + 64) * 4 + h] + asd[h];
        float e0 = a0 > 0.f ? a0 : 0.2f * a0;     // leaky_relu 0.2
        float e1 = a1 > 0.f ? a1 : 0.2f * a1;
        float mx = fmaxf(e0, e1);
        #pragma unroll
        for (int m = 32; m >= 1; m >>= 1) mx = fmaxf(mx, __shfl_xor(mx, m, 64));
        float p0 = __expf(e0 - mx), p1 = __expf(e1 - mx);
        float s = p0 + p1;
        #pragma unroll
        for (int m = 32; m >= 1; m >>= 1) s += __shfl_xor(s, m, 64);
        float inv = 1.f / s;
        wgt[j * 4 + h] = p0 * inv;
        wgt[(j + 64) * 4 + h] = p1 * inv;
    }
    __syncthreads();

    // m[h][f] = sum_j wgt[j][h] * xh[j][f]   (lane f consecutive -> coalesced)
    #pragma unroll
    for (int p2 = 0; p2 < 2; ++p2) {
        int p = p2 * 256 + tid;
        int h = p >> 7, f = p & 127;
        float acc = 0.f;
        for (int j = 0; j < 128; ++j)
            acc = fmaf(wgt[j * 4 + h], xb[j * 128 + f], acc);
        m_l[h * 128 + f] = acc;
    }
    __syncthreads();

    // out[b][c] = 0.25 * sum_h sum_f m[h][f] * W[h][c][f] + bias[c]
    if (tid < 128) {
        int c = tid;
        float acc = 0.f;
        #pragma unroll
        for (int h = 0; h < 4; ++h) {
            const float* wrp = gat_w + (h * 128 + c) * 128;
            const float* mr  = m_l + h * 128;
            for (int f = 0; f < 128; f += 4) {
                f32x4 wvv = *(const f32x4*)&wrp[f];
                f32x4 mv  = *(const f32x4*)&mr[f];
                acc += wvv[0] * mv[0] + wvv[1] * mv[1] + wvv[2] * mv[2] + wvv[3] * mv[3];
            }
        }
        out[b * 128 + c] = 0.25f * acc + gbias[c];
    }
}

// ---------------------------------------------------------------------------
extern "C" void kernel_launch(void* const* d_in, const int* in_sizes, int n_in,
                              void* d_out, int out_size, void* d_ws, size_t ws_size,
                              hipStream_t stream) {
    const float* x       = (const float*)d_in[0];
    const float* wih     = (const float*)d_in[1];
    const float* whh     = (const float*)d_in[2];
    const float* bih     = (const float*)d_in[3];
    const float* bhh     = (const float*)d_in[4];
    const float* gat_w   = (const float*)d_in[5];
    const float* att_src = (const float*)d_in[6];
    const float* att_dst = (const float*)d_in[7];
    const float* gbias   = (const float*)d_in[8];
    float* outp = (float*)d_out;

    float* xh = (float*)d_ws;              // 16384*128 f32 (8.39 MB)

    gru_kernel<<<1024, 256, 0, stream>>>(x, wih, whh, bih, bhh, xh);
    gat_kernel<<<128, 256, 0, stream>>>(xh, gat_w, att_src, att_dst, gbias, outp);
}

// Round 10
// 400.446 us; speedup vs baseline: 5.5331x; 1.0191x over previous
//
#include <hip/hip_runtime.h>

// B=128, N=128, L=128 -> BN=16384 rows, T=127 steps, HID=CD=128, HEADS=4.
// v8 = v7 + (a) cheap native fallback for exp2 (__expf(x*ln2), 3 instr) in case
// __builtin_amdgcn_exp2f doesn't exist (v7 post-mortem: ~2x VALU bloat, 4100
// VALU-cy/SIMD/step vs ~2000 modeled; OCML exp2f libcall is prime suspect);
// (b) f_lds padded [128][17] to kill 64-way phase-write bank conflicts.
// VGPR kept at 128 (no new hoisting) -- crossing 128 halves occupancy (v5 lesson).
// (Resubmission: round-9 bench never acquired a GPU.)

#define BN_TOT 16384
#define TSTEPS 127
#define LOG2E  1.44269504f
#define LN2    0.69314718f

#ifndef __has_builtin
#define __has_builtin(x) 0
#endif
#if __has_builtin(__builtin_amdgcn_exp2f)
#define EXP2F(x) __builtin_amdgcn_exp2f(x)
#else
#define EXP2F(x) __expf((x) * LN2)   // native v_mul+v_exp, not OCML libcall
#endif
#if __has_builtin(__builtin_amdgcn_sqrtf)
#define FSQRT(x) __builtin_amdgcn_sqrtf(x)
#else
#define FSQRT(x) sqrtf(x)
#endif

typedef _Float16 f16x8 __attribute__((ext_vector_type(8)));
typedef float    f32x4 __attribute__((ext_vector_type(4)));

// acos for x in [0,1]: Abramowitz-Stegun 4.4.45, max err ~6.7e-5 rad.
__device__ __forceinline__ float acos01(float x) {
    float s = FSQRT(1.0f - x);
    float p = fmaf(x, -0.0187293f, 0.0742610f);
    p = fmaf(x, p, -0.2121144f);
    p = fmaf(x, p, 1.5707288f);
    return s * p;
}

// ---------------------------------------------------------------------------
// Kernel 1: fused features + GRU.
// 1024 blocks x 256 thr (4 waves). Block owns 16 rows; wave wv owns cols
// [32wv, 32wv+32). whh B-frags register-resident, prescaled by log2e (r,z) /
// 2*log2e (n). h double-buffered in LDS fp16, XOR swizzle (col ^ ((row&7)<<3)),
// ONE barrier per step (LDS-only drain).
// MFMA 16x16x32 f16: A lane l -> row=l&15, k=(l>>4)*8+j ; B lane l -> col=l&15,
// same k ; C lane l reg i -> row=(l>>4)*4+i, col=l&15.
// ---------------------------------------------------------------------------
__global__ __launch_bounds__(256, 2) void gru_kernel(
    const float* __restrict__ x,     // [BN][128][2]
    const float* __restrict__ wih,   // [384][2]
    const float* __restrict__ whh,   // [384][128]
    const float* __restrict__ bih,   // [384]
    const float* __restrict__ bhh,   // [384]
    float* __restrict__ xh)          // [BN][128]
{
    __shared__ __align__(16) _Float16 h_l[2][16 * 128];  // 8 KB double-buffered
    __shared__ __align__(16) float2   f_lds[128][17];    // 17.4 KB: [t][row(+pad)]={v,ang}

    const int tid  = threadIdx.x;
    const int wv   = tid >> 6;          // wave 0..3 -> cols [32wv, 32wv+32)
    const int lane = tid & 63;
    const int c0   = lane & 15;
    const int rg   = lane >> 4;
    const int rbase = blockIdx.x * 16;

    // ---- whh B-frags -> registers, prescaled ----
    f16x8 wr[2][4], wz[2][4], wn[2][4];
    float w0r[2], w1r[2], bbr[2], w0z[2], w1z[2], bbz[2];
    float w0n[2], w1n[2], bin_[2], bhn_[2];
    #pragma unroll
    for (int ct = 0; ct < 2; ++ct) {
        const int gr = wv * 32 + ct * 16 + c0;   // r-gate row of whh
        const int gz = gr + 128;                 // z
        const int gn = gr + 256;                 // n
        #pragma unroll
        for (int kt = 0; kt < 4; ++kt) {
            int ko = kt * 32 + rg * 8;
            f32x4 r0 = *(const f32x4*)&whh[gr * 128 + ko];
            f32x4 r1 = *(const f32x4*)&whh[gr * 128 + ko + 4];
            f32x4 z0 = *(const f32x4*)&whh[gz * 128 + ko];
            f32x4 z1 = *(const f32x4*)&whh[gz * 128 + ko + 4];
            f32x4 n0 = *(const f32x4*)&whh[gn * 128 + ko];
            f32x4 n1 = *(const f32x4*)&whh[gn * 128 + ko + 4];
            f16x8 fr, fz, fn;
            #pragma unroll
            for (int j = 0; j < 4; ++j) {
                fr[j]     = (_Float16)(r0[j] * LOG2E);
                fr[j + 4] = (_Float16)(r1[j] * LOG2E);
                fz[j]     = (_Float16)(z0[j] * LOG2E);
                fz[j + 4] = (_Float16)(z1[j] * LOG2E);
                fn[j]     = (_Float16)(n0[j] * (2.f * LOG2E));
                fn[j + 4] = (_Float16)(n1[j] * (2.f * LOG2E));
            }
            wr[ct][kt] = fr; wz[ct][kt] = fz; wn[ct][kt] = fn;
        }
        w0r[ct] = wih[gr * 2] * LOG2E;        w1r[ct] = wih[gr * 2 + 1] * LOG2E;
        w0z[ct] = wih[gz * 2] * LOG2E;        w1z[ct] = wih[gz * 2 + 1] * LOG2E;
        w0n[ct] = wih[gn * 2] * 2.f * LOG2E;  w1n[ct] = wih[gn * 2 + 1] * 2.f * LOG2E;
        bbr[ct] = (bih[gr] + bhh[gr]) * LOG2E;
        bbz[ct] = (bih[gz] + bhh[gz]) * LOG2E;
        bin_[ct] = bih[gn] * 2.f * LOG2E;     // outside r*( )
        bhn_[ct] = bhh[gn] * 2.f * LOG2E;     // inside r*( ) -> MFMA acc init
    }

    // ---- phase 1: speeds v[row][t] = |x[t+1]-x[t]|, t-parallel, coalesced ----
    const float2* xp = (const float2*)x;
    #pragma unroll
    for (int i = 0; i < 8; ++i) {
        int p = i * 256 + tid;          // 0..2047
        int row = p >> 7, t = p & 127;
        if (t < TSTEPS) {
            float2 a = xp[(rbase + row) * 128 + t];
            float2 b = xp[(rbase + row) * 128 + t + 1];
            float dx = b.x - a.x, dy = b.y - a.y;
            f_lds[t][row].x = FSQRT(fmaf(dx, dx, dy * dy));
        }
    }
    // ---- zero h buffer 0 (h0 = 0): 16*128 halves = 1024 ints ----
    {
        int* hz = (int*)h_l[0];
        #pragma unroll
        for (int i = 0; i < 4; ++i) hz[i * 256 + tid] = 0;
    }
    __syncthreads();

    // ---- phase 2: angles (reads .x of t and t-1, writes .y: no race) ----
    #pragma unroll
    for (int i = 0; i < 8; ++i) {
        int p = i * 256 + tid;
        int row = p >> 7, t = p & 127;
        if (t < TSTEPS) {
            float v  = f_lds[t][row].x;
            float pv = f_lds[(t == 0) ? 0 : (t - 1)][row].x;
            float num = pv * v;
            float den = (pv + 1e-6f) * (v + 1e-6f);
            float cs  = fminf(num * __builtin_amdgcn_rcpf(den), 1.0f);  // in [0,1]
            f_lds[t][row].y = acos01(cs);
        }
    }
    __syncthreads();

    float h_reg[2][4];   // [ct][i]; row=rg*4+i, col=wv*32+ct*16+c0
    #pragma unroll
    for (int ct = 0; ct < 2; ++ct)
        #pragma unroll
        for (int i = 0; i < 4; ++i) h_reg[ct][i] = 0.f;

    const int swz_a = (c0 & 7) << 3;

    #pragma unroll 1
    for (int t = 0; t < TSTEPS; ++t) {
        const _Float16* hb = h_l[t & 1];
        _Float16*       hw = h_l[(t & 1) ^ 1];

        // features of the 4 rows (rg*4 .. rg*4+3): 4 x ds_read_b64, bank-spread
        float2 fv0 = f_lds[t][rg * 4 + 0];
        float2 fv1 = f_lds[t][rg * 4 + 1];
        float2 fv2 = f_lds[t][rg * 4 + 2];
        float2 fv3 = f_lds[t][rg * 4 + 3];
        float vv[4] = {fv0.x, fv1.x, fv2.x, fv3.x};
        float aa[4] = {fv0.y, fv1.y, fv2.y, fv3.y};

        // A-frags: h_prev[c0][k], swizzle keyed by row&7 = c0&7
        f16x8 afr[4];
        #pragma unroll
        for (int kt = 0; kt < 4; ++kt) {
            int ko = kt * 32 + rg * 8;
            afr[kt] = *(const f16x8*)&hb[c0 * 128 + (ko ^ swz_a)];
        }

        #pragma unroll
        for (int ct = 0; ct < 2; ++ct) {
            // acc init = input-gate part + folded biases (prescaled)
            f32x4 ar, az, an_;
            float gxn[4];
            #pragma unroll
            for (int i = 0; i < 4; ++i) {
                ar[i]  = fmaf(vv[i], w0r[ct], fmaf(aa[i], w1r[ct], bbr[ct]));
                az[i]  = fmaf(vv[i], w0z[ct], fmaf(aa[i], w1z[ct], bbz[ct]));
                an_[i] = bhn_[ct];
                gxn[i] = fmaf(vv[i], w0n[ct], fmaf(aa[i], w1n[ct], bin_[ct]));
            }
            #pragma unroll
            for (int kt = 0; kt < 4; ++kt) {
                ar  = __builtin_amdgcn_mfma_f32_16x16x32_f16(afr[kt], wr[ct][kt], ar,  0, 0, 0);
                az  = __builtin_amdgcn_mfma_f32_16x16x32_f16(afr[kt], wz[ct][kt], az,  0, 0, 0);
                an_ = __builtin_amdgcn_mfma_f32_16x16x32_f16(afr[kt], wn[ct][kt], an_, 0, 0, 0);
            }
            // r = sigma, z = sigma, nn = tanh(.) -- args prescaled for exp2
            #pragma unroll
            for (int i = 0; i < 4; ++i) {
                float r  = __builtin_amdgcn_rcpf(1.f + EXP2F(-ar[i]));
                float z  = __builtin_amdgcn_rcpf(1.f + EXP2F(-az[i]));
                float sn = fmaf(r, an_[i], gxn[i]);
                float nn = fmaf(-2.f, __builtin_amdgcn_rcpf(1.f + EXP2F(sn)), 1.f);
                float hv = h_reg[ct][i];
                hv = fmaf(z, hv - nn, nn);          // (1-z)*nn + z*h
                h_reg[ct][i] = hv;
                int row = rg * 4 + i;
                int col = wv * 32 + ct * 16 + c0;
                hw[row * 128 + (col ^ ((row & 7) << 3))] = (_Float16)hv;
            }
        }
        __syncthreads();
    }

    // ---- store final h ----
    #pragma unroll
    for (int ct = 0; ct < 2; ++ct)
        #pragma unroll
        for (int i = 0; i < 4; ++i) {
            int r = rbase + rg * 4 + i;
            xh[r * 128 + wv * 32 + ct * 16 + c0] = h_reg[ct][i];
        }
}

// ---------------------------------------------------------------------------
// Kernel 2: collapsed DenseGATConv for node i=0, weff folded in.
// One block per batch b. xh[b] (64KB) is L2-resident; reads are coalesced.
// ---------------------------------------------------------------------------
__global__ __launch_bounds__(256) void gat_kernel(
    const float* __restrict__ xh,      // [B*N][128]
    const float* __restrict__ gat_w,   // [512][128]  (= [h][c][f])
    const float* __restrict__ att_src, // [4][128]
    const float* __restrict__ att_dst, // [4][128]
    const float* __restrict__ gbias,   // [128]
    float* __restrict__ out)           // [B][128]
{
    __shared__ __align__(16) float wse_l[512];    // [h][f]
    __shared__ __align__(16) float wde_l[512];    // [h][f]
    __shared__ float asrc[512];                   // [j][h]
    __shared__ float wgt[512];                    // [j][h]
    __shared__ __align__(16) float m_l[512];      // [h][f]
    __shared__ float asd[4];

    const int b = blockIdx.x, tid = threadIdx.x;
    const float* xb = xh + b * 16384;

    // phase 0: ws_eff[h][f] = sum_c att[h][c] * W[h][c][f]  (coalesced over f)
    #pragma unroll
    for (int p2 = 0; p2 < 2; ++p2) {
        int p = p2 * 256 + tid;
        int h = p >> 7, f = p & 127;
        float ss = 0.f, dd = 0.f;
        for (int c = 0; c < 128; ++c) {
            float w = gat_w[(h * 128 + c) * 128 + f];
            ss = fmaf(att_src[h * 128 + c], w, ss);
            dd = fmaf(att_dst[h * 128 + c], w, dd);
        }
        wse_l[p] = ss;
        wde_l[p] = dd;
    }
    __syncthreads();

    // a_src[j][h] = xh[j] . wse[h]   (4 lanes share each xh 16B read)
    #pragma unroll
    for (int p2 = 0; p2 < 2; ++p2) {
        int p = p2 * 256 + tid;
        int j = p >> 2, h = p & 3;
        const float* wrp = wse_l + h * 128;
        const float* xr  = xb + j * 128;
        float acc = 0.f;
        for (int f = 0; f < 128; f += 4) {
            f32x4 xv  = *(const f32x4*)&xr[f];
            f32x4 wvv = *(const f32x4*)&wrp[f];
            acc += xv[0] * wvv[0] + xv[1] * wvv[1] + xv[2] * wvv[2] + xv[3] * wvv[3];
        }
        asrc[j * 4 + h] = acc;
    }
    if (tid < 4) {     // a_dst at node 0
        const float* wrp = wde_l + tid * 128;
        float acc = 0.f;
        for (int f = 0; f < 128; f += 4) {
            f32x4 xv  = *(const f32x4*)&xb[f];
            f32x4 wvv = *(const f32x4*)&wrp[f];
            acc += xv[0] * wvv[0] + xv[1] * wvv[1] + xv[2] * wvv[2] + xv[3] * wvv[3];
        }
        asd[tid] = acc;
    }
    __syncthreads();

    // per-head softmax over j (wave h handles head h; lanes hold j and j+64)
    {
        int h = tid >> 6, j = tid & 63;
        float a0 = asrc[j * 4 + h] + asd[h];
        float a1 = asrc[(j + 64) * 4 + h] + asd[h];
        float e0 = a0 > 0.f ? a0 : 0.2f * a0;     // leaky_relu 0.2
        float e1 = a1 > 0.f ? a1 : 0.2f * a1;
        float mx = fmaxf(e0, e1);
        #pragma unroll
        for (int m = 32; m >= 1; m >>= 1) mx = fmaxf(mx, __shfl_xor(mx, m, 64));
        float p0 = __expf(e0 - mx), p1 = __expf(e1 - mx);
        float s = p0 + p1;
        #pragma unroll
        for (int m = 32; m >= 1; m >>= 1) s += __shfl_xor(s, m, 64);
        float inv = 1.f / s;
        wgt[j * 4 + h] = p0 * inv;
        wgt[(j + 64) * 4 + h] = p1 * inv;
    }
    __syncthreads();

    // m[h][f] = sum_j wgt[j][h] * xh[j][f]   (lane f consecutive -> coalesced)
    #pragma unroll
    for (int p2 = 0; p2 < 2; ++p2) {
        int p = p2 * 256 + tid;
        int h = p >> 7, f = p & 127;
        float acc = 0.f;
        for (int j = 0; j < 128; ++j)
            acc = fmaf(wgt[j * 4 + h], xb[j * 128 + f], acc);
        m_l[h * 128 + f] = acc;
    }
    __syncthreads();

    // out[b][c] = 0.25 * sum_h sum_f m[h][f] * W[h][c][f] + bias[c]
    if (tid < 128) {
        int c = tid;
        float acc = 0.f;
        #pragma unroll
        for (int h = 0; h < 4; ++h) {
            const float* wrp = gat_w + (h * 128 + c) * 128;
            const float* mr  = m_l + h * 128;
            for (int f = 0; f < 128; f += 4) {
                f32x4 wvv = *(const f32x4*)&wrp[f];
                f32x4 mv  = *(const f32x4*)&mr[f];
                acc += wvv[0] * mv[0] + wvv[1] * mv[1] + wvv[2] * mv[2] + wvv[3] * mv[3];
            }
        }
        out[b * 128 + c] = 0.25f * acc + gbias[c];
    }
}

// ---------------------------------------------------------------------------
extern "C" void kernel_launch(void* const* d_in, const int* in_sizes, int n_in,
                              void* d_out, int out_size, void* d_ws, size_t ws_size,
                              hipStream_t stream) {
    const float* x       = (const float*)d_in[0];
    const float* wih     = (const float*)d_in[1];
    const float* whh     = (const float*)d_in[2];
    const float* bih     = (const float*)d_in[3];
    const float* bhh     = (const float*)d_in[4];
    const float* gat_w   = (const float*)d_in[5];
    const float* att_src = (const float*)d_in[6];
    const float* att_dst = (const float*)d_in[7];
    const float* gbias   = (const float*)d_in[8];
    float* outp = (float*)d_out;

    float* xh = (float*)d_ws;              // 16384*128 f32 (8.39 MB)

    gru_kernel<<<1024, 256, 0, stream>>>(x, wih, whh, bih, bhh, xh);
    gat_kernel<<<128, 256, 0, stream>>>(xh, gat_w, att_src, att_dst, gbias, outp);
}